// Round 1
// baseline (1130.321 us; speedup 1.0000x reference)
//
#include <hip/hip_runtime.h>

#define SCALE 0.08838834764831845f

constexpr int B_    = 32;
constexpr int H_    = 32;
constexpr int KVH_  = 8;
constexpr int G_    = 4;     // H / KVH
constexpr int D_    = 128;
constexpr int BS_   = 128;   // cache block size
constexpr int MAXB_ = 32;    // max blocks per seq
constexpr int SMAX_ = 4096;  // MAXB_*BS_
constexpr int NSPLIT = 8;
constexpr int CHUNK  = SMAX_ / NSPLIT;       // 512 positions per split
constexpr int NBLK_PER_CHUNK = CHUNK / BS_;  // 4 cache blocks per split

// ---------------------------------------------------------------------------
// Kernel 1: per (b, kvh, split) partial attention over a 512-position chunk.
// 256 threads = 8 groups of 32 lanes; each group owns positions i = grp + 8k.
// K/V reads: 32 lanes x float4 = 512 B contiguous per position (coalesced).
// ---------------------------------------------------------------------------
__global__ __launch_bounds__(256) void attn_partial(
    const float* __restrict__ q,        // [B,H,D]
    const float* __restrict__ kc,       // [NB,BS,KVH,D]
    const float* __restrict__ vc,       // [NB,BS,KVH,D]
    const int*   __restrict__ bt,       // [B,MAXB]
    const int*   __restrict__ ctxl,     // [B]
    float*       __restrict__ part_o,   // [B,KVH,NSPLIT,G,D]
    float*       __restrict__ part_ml)  // [B,KVH,NSPLIT,G,2]
{
    const int bid   = blockIdx.x;
    const int split = bid & (NSPLIT - 1);
    const int kv    = (bid >> 3) & (KVH_ - 1);
    const int b     = bid >> 6;  // / (NSPLIT*KVH_)
    const int tid   = threadIdx.x;

    const int ctx   = ctxl[b];
    const int start = split * CHUNK;
    int clen = ctx - start;
    if (clen > CHUNK) clen = CHUNK;

    const int mlbase = ((b * KVH_ + kv) * NSPLIT + split) * G_ * 2;
    if (clen <= 0) {
        // no valid positions in this split: mark l=0 so reducer skips it
        if (tid < G_) {
            part_ml[mlbase + tid * 2 + 0] = -__builtin_inff();
            part_ml[mlbase + tid * 2 + 1] = 0.f;
        }
        return;
    }

    __shared__ float q_s[G_ * D_];        // 2 KB
    __shared__ float logit[G_][CHUNK];    // 8 KB (scores, then weights)
    __shared__ float red[8 * G_ * D_];    // 16 KB cross-group o reduction
    __shared__ int   blk_s[NBLK_PER_CHUNK];
    __shared__ float red_m[4][G_];
    __shared__ float red_l[4][G_];

    // load scaled Q for this kv-head group
    for (int i = tid; i < G_ * D_; i += 256) {
        int g = i >> 7, d = i & (D_ - 1);
        q_s[i] = q[((size_t)b * H_ + kv * G_ + g) * D_ + d] * SCALE;
    }
    if (tid < NBLK_PER_CHUNK)
        blk_s[tid] = bt[b * MAXB_ + split * NBLK_PER_CHUNK + tid];
    __syncthreads();

    const int lane = tid & 31;
    const int grp  = tid >> 5;

    float4 qr[G_];
#pragma unroll
    for (int g = 0; g < G_; g++)
        qr[g] = ((const float4*)(q_s + g * D_))[lane];

    // ---------------- Phase A: scores = Q . K ----------------
    for (int i = grp; i < clen; i += 8) {
        const int blk = blk_s[i >> 7];
        const int off = i & (BS_ - 1);
        const float4* kp =
            (const float4*)(kc + (((size_t)blk * BS_ + off) * KVH_ + kv) * D_);
        float4 k4 = kp[lane];
        float s[G_];
#pragma unroll
        for (int g = 0; g < G_; g++)
            s[g] = k4.x * qr[g].x + k4.y * qr[g].y + k4.z * qr[g].z + k4.w * qr[g].w;
#pragma unroll
        for (int m = 16; m >= 1; m >>= 1) {
#pragma unroll
            for (int g = 0; g < G_; g++)
                s[g] += __shfl_xor(s[g], m, 64);
        }
        if (lane == 0) {
#pragma unroll
            for (int g = 0; g < G_; g++) logit[g][i] = s[g];
        }
    }
    __syncthreads();

    // ---------------- Phase B: softmax (max, exp, sum) ----------------
    float ml[G_];
#pragma unroll
    for (int g = 0; g < G_; g++) ml[g] = -__builtin_inff();
    for (int i = tid; i < clen; i += 256) {
#pragma unroll
        for (int g = 0; g < G_; g++) ml[g] = fmaxf(ml[g], logit[g][i]);
    }
#pragma unroll
    for (int m = 32; m >= 1; m >>= 1) {
#pragma unroll
        for (int g = 0; g < G_; g++)
            ml[g] = fmaxf(ml[g], __shfl_xor(ml[g], m, 64));
    }
    if ((tid & 63) == 0) {
#pragma unroll
        for (int g = 0; g < G_; g++) red_m[tid >> 6][g] = ml[g];
    }
    __syncthreads();
    float M[G_];
#pragma unroll
    for (int g = 0; g < G_; g++)
        M[g] = fmaxf(fmaxf(red_m[0][g], red_m[1][g]),
                     fmaxf(red_m[2][g], red_m[3][g]));

    float ll[G_] = {0.f, 0.f, 0.f, 0.f};
    for (int i = tid; i < clen; i += 256) {
#pragma unroll
        for (int g = 0; g < G_; g++) {
            float p = __expf(logit[g][i] - M[g]);
            logit[g][i] = p;
            ll[g] += p;
        }
    }
#pragma unroll
    for (int m = 32; m >= 1; m >>= 1) {
#pragma unroll
        for (int g = 0; g < G_; g++) ll[g] += __shfl_xor(ll[g], m, 64);
    }
    if ((tid & 63) == 0) {
#pragma unroll
        for (int g = 0; g < G_; g++) red_l[tid >> 6][g] = ll[g];
    }
    __syncthreads();
    float L[G_];
#pragma unroll
    for (int g = 0; g < G_; g++)
        L[g] = red_l[0][g] + red_l[1][g] + red_l[2][g] + red_l[3][g];

    // ---------------- Phase C: o = P . V ----------------
    float4 acc[G_] = {};
    for (int i = grp; i < clen; i += 8) {
        const int blk = blk_s[i >> 7];
        const int off = i & (BS_ - 1);
        const float4* vp =
            (const float4*)(vc + (((size_t)blk * BS_ + off) * KVH_ + kv) * D_);
        float4 v4 = vp[lane];
#pragma unroll
        for (int g = 0; g < G_; g++) {
            float w = logit[g][i];  // LDS broadcast within group
            acc[g].x += w * v4.x; acc[g].y += w * v4.y;
            acc[g].z += w * v4.z; acc[g].w += w * v4.w;
        }
    }
    // cross-group reduction of partial o
    float4* red4 = (float4*)red;
#pragma unroll
    for (int g = 0; g < G_; g++)
        red4[(grp * G_ + g) * 32 + lane] = acc[g];
    __syncthreads();

    const size_t obase = (size_t)((b * KVH_ + kv) * NSPLIT + split) * (G_ * D_);
    for (int e = tid; e < G_ * D_; e += 256) {
        float sum = 0.f;
#pragma unroll
        for (int p = 0; p < 8; p++) sum += red[p * (G_ * D_) + e];
        part_o[obase + e] = sum;
    }
    if (tid == 0) {
#pragma unroll
        for (int g = 0; g < G_; g++) {
            part_ml[mlbase + g * 2 + 0] = M[g];
            part_ml[mlbase + g * 2 + 1] = L[g];
        }
    }
}

// ---------------------------------------------------------------------------
// Kernel 2: merge NSPLIT partials per (b, kvh) via log-sum-exp combination.
// ---------------------------------------------------------------------------
__global__ __launch_bounds__(256) void attn_reduce(
    const float* __restrict__ part_o,
    const float* __restrict__ part_ml,
    float*       __restrict__ out)  // [B,H,D]
{
    const int bid = blockIdx.x;  // b*KVH + kv
    const int tid = threadIdx.x;

    __shared__ float sc[G_][NSPLIT];
    __shared__ float Ls[G_];

    if (tid < G_) {
        float m = -__builtin_inff();
        float lv[NSPLIT], mv[NSPLIT];
#pragma unroll
        for (int s = 0; s < NSPLIT; s++) {
            mv[s] = part_ml[((size_t)bid * NSPLIT + s) * G_ * 2 + tid * 2 + 0];
            lv[s] = part_ml[((size_t)bid * NSPLIT + s) * G_ * 2 + tid * 2 + 1];
            if (lv[s] > 0.f) m = fmaxf(m, mv[s]);
        }
        float L = 0.f;
#pragma unroll
        for (int s = 0; s < NSPLIT; s++) {
            float f = (lv[s] > 0.f) ? __expf(mv[s] - m) : 0.f;
            sc[tid][s] = f;
            L += f * lv[s];
        }
        Ls[tid] = L;
    }
    __syncthreads();

    for (int e = tid; e < G_ * D_; e += 256) {
        int g = e >> 7;
        float a = 0.f;
#pragma unroll
        for (int s = 0; s < NSPLIT; s++) {
            float f = sc[g][s];
            if (f != 0.f)
                a += f * part_o[((size_t)bid * NSPLIT + s) * (G_ * D_) + e];
        }
        // out flat index: b*H*D + (kv*G+g)*D + d == bid*(G_*D_) + e
        out[(size_t)bid * (G_ * D_) + e] = a / Ls[g];
    }
}

extern "C" void kernel_launch(void* const* d_in, const int* in_sizes, int n_in,
                              void* d_out, int out_size, void* d_ws, size_t ws_size,
                              hipStream_t stream) {
    const float* q   = (const float*)d_in[0];
    const float* kc  = (const float*)d_in[1];
    const float* vc  = (const float*)d_in[2];
    const int*   bt  = (const int*)d_in[3];
    const int*   ctx = (const int*)d_in[4];
    float* out = (float*)d_out;

    float* part_o  = (float*)d_ws;  // B*KVH*NSPLIT*G*D floats = 4 MB
    float* part_ml = part_o + (size_t)B_ * KVH_ * NSPLIT * G_ * D_;  // +16 KB

    attn_partial<<<B_ * KVH_ * NSPLIT, 256, 0, stream>>>(q, kc, vc, bt, ctx,
                                                         part_o, part_ml);
    attn_reduce<<<B_ * KVH_, 256, 0, stream>>>(part_o, part_ml, out);
}

// Round 2
// 1063.968 us; speedup vs baseline: 1.0624x; 1.0624x over previous
//
#include <hip/hip_runtime.h>

#define SCALE 0.08838834764831845f

constexpr int B_    = 32;
constexpr int H_    = 32;
constexpr int KVH_  = 8;
constexpr int G_    = 4;     // H / KVH
constexpr int D_    = 128;
constexpr int BS_   = 128;   // cache block size
constexpr int MAXB_ = 32;    // max blocks per seq
constexpr int NSPLIT = 8;
constexpr int CHUNK  = 4096 / NSPLIT;        // 512 positions per split
constexpr int NBLK_PER_CHUNK = CHUNK / BS_;  // 4 cache blocks per split

// ---------------------------------------------------------------------------
// Kernel 1: per (b, kvh, split) partial attention over a 512-position chunk.
//
// Phase A (QK^T): 16 lanes per position (cluster c = tid>>4 owns positions
//   p = c + 16k). Each lane loads 2 float4 K-chunks (ln16, ln16+16); Q
//   fragments live in 32 VGPRs; 4-stage butterfly (xor 1,2,4,8) instead of
//   the previous 5-stage/position — VALU drops ~46 -> ~32 cyc/position,
//   below the 50 cyc/position HBM fair-share budget (memory-bound now).
// Phase C (PV): 32 lanes per position (group g = tid>>5), weights broadcast
//   from LDS; already has VALU slack.
// ---------------------------------------------------------------------------
__global__ __launch_bounds__(256) void attn_partial(
    const float* __restrict__ q,        // [B,H,D]
    const float* __restrict__ kc,       // [NB,BS,KVH,D]
    const float* __restrict__ vc,       // [NB,BS,KVH,D]
    const int*   __restrict__ bt,       // [B,MAXB]
    const int*   __restrict__ ctxl,     // [B]
    float*       __restrict__ part_o,   // [B,KVH,NSPLIT,G,D]
    float*       __restrict__ part_ml)  // [B,KVH,NSPLIT,G,2]
{
    const int bid   = blockIdx.x;
    const int split = bid & (NSPLIT - 1);
    const int kv    = (bid >> 3) & (KVH_ - 1);
    const int b     = bid >> 6;
    const int tid   = threadIdx.x;

    const int ctx   = ctxl[b];
    const int start = split * CHUNK;
    int clen = ctx - start;
    if (clen > CHUNK) clen = CHUNK;

    const int mlbase = ((b * KVH_ + kv) * NSPLIT + split) * G_ * 2;
    if (clen <= 0) {
        if (tid < G_) {
            part_ml[mlbase + tid * 2 + 0] = -__builtin_inff();
            part_ml[mlbase + tid * 2 + 1] = 0.f;
        }
        return;
    }

    __shared__ float q_s[G_ * D_];        // 2 KB
    __shared__ float logit[G_][CHUNK];    // 8 KB (scores, then weights)
    __shared__ float red[8 * G_ * D_];    // 16 KB cross-group o reduction
    __shared__ int   blk_s[NBLK_PER_CHUNK];
    __shared__ float red_m[4][G_];
    __shared__ float red_l[4][G_];

    for (int i = tid; i < G_ * D_; i += 256) {
        int g = i >> 7, d = i & (D_ - 1);
        q_s[i] = q[((size_t)b * H_ + kv * G_ + g) * D_ + d] * SCALE;
    }
    if (tid < NBLK_PER_CHUNK)
        blk_s[tid] = bt[b * MAXB_ + split * NBLK_PER_CHUNK + tid];
    __syncthreads();

    // ---------------- Phase A: scores = Q . K (16 lanes / position) --------
    {
        const int ln16 = tid & 15;
        const int cl   = tid >> 4;   // cluster 0..15, owns position p = cl+16k

        float4 qr[G_][2];
#pragma unroll
        for (int g = 0; g < G_; g++) {
            const float4* qp = (const float4*)(q_s + g * D_);
            qr[g][0] = qp[ln16];
            qr[g][1] = qp[ln16 + 16];
        }

#pragma unroll 2
        for (int p = cl; p < clen; p += 16) {
            const int blk = blk_s[p >> 7];
            const int off = p & (BS_ - 1);
            const float4* kp =
                (const float4*)(kc + ((((size_t)blk * BS_ + off) * KVH_ + kv) << 7))
                + ln16;
            float4 ka = kp[0];
            float4 kb = kp[16];
            float s[G_];
#pragma unroll
            for (int g = 0; g < G_; g++) {
                s[g] = ka.x * qr[g][0].x + ka.y * qr[g][0].y +
                       ka.z * qr[g][0].z + ka.w * qr[g][0].w +
                       kb.x * qr[g][1].x + kb.y * qr[g][1].y +
                       kb.z * qr[g][1].z + kb.w * qr[g][1].w;
            }
#pragma unroll
            for (int m = 8; m >= 1; m >>= 1) {
#pragma unroll
                for (int g = 0; g < G_; g++)
                    s[g] += __shfl_xor(s[g], m, 64);
            }
            if (ln16 == 0) {
#pragma unroll
                for (int g = 0; g < G_; g++) logit[g][p] = s[g];
            }
        }
    }
    __syncthreads();

    // ---------------- Phase B: softmax (max, exp, sum) ----------------
    float ml[G_];
#pragma unroll
    for (int g = 0; g < G_; g++) ml[g] = -__builtin_inff();
    for (int i = tid; i < clen; i += 256) {
#pragma unroll
        for (int g = 0; g < G_; g++) ml[g] = fmaxf(ml[g], logit[g][i]);
    }
#pragma unroll
    for (int m = 32; m >= 1; m >>= 1) {
#pragma unroll
        for (int g = 0; g < G_; g++)
            ml[g] = fmaxf(ml[g], __shfl_xor(ml[g], m, 64));
    }
    if ((tid & 63) == 0) {
#pragma unroll
        for (int g = 0; g < G_; g++) red_m[tid >> 6][g] = ml[g];
    }
    __syncthreads();
    float M[G_];
#pragma unroll
    for (int g = 0; g < G_; g++)
        M[g] = fmaxf(fmaxf(red_m[0][g], red_m[1][g]),
                     fmaxf(red_m[2][g], red_m[3][g]));

    float ll[G_] = {0.f, 0.f, 0.f, 0.f};
    for (int i = tid; i < clen; i += 256) {
#pragma unroll
        for (int g = 0; g < G_; g++) {
            float pv = __expf(logit[g][i] - M[g]);
            logit[g][i] = pv;
            ll[g] += pv;
        }
    }
#pragma unroll
    for (int m = 32; m >= 1; m >>= 1) {
#pragma unroll
        for (int g = 0; g < G_; g++) ll[g] += __shfl_xor(ll[g], m, 64);
    }
    if ((tid & 63) == 0) {
#pragma unroll
        for (int g = 0; g < G_; g++) red_l[tid >> 6][g] = ll[g];
    }
    __syncthreads();
    float L[G_];
#pragma unroll
    for (int g = 0; g < G_; g++)
        L[g] = red_l[0][g] + red_l[1][g] + red_l[2][g] + red_l[3][g];

    // ---------------- Phase C: o = P . V (32 lanes / position) --------
    const int lane = tid & 31;
    const int grp  = tid >> 5;

    float4 acc[G_] = {};
#pragma unroll 2
    for (int i = grp; i < clen; i += 8) {
        const int blk = blk_s[i >> 7];
        const int off = i & (BS_ - 1);
        const float4* vp =
            (const float4*)(vc + ((((size_t)blk * BS_ + off) * KVH_ + kv) << 7));
        float4 v4 = vp[lane];
#pragma unroll
        for (int g = 0; g < G_; g++) {
            float w = logit[g][i];  // LDS broadcast within group
            acc[g].x += w * v4.x; acc[g].y += w * v4.y;
            acc[g].z += w * v4.z; acc[g].w += w * v4.w;
        }
    }
    float4* red4 = (float4*)red;
#pragma unroll
    for (int g = 0; g < G_; g++)
        red4[(grp * G_ + g) * 32 + lane] = acc[g];
    __syncthreads();

    const size_t obase = (size_t)((b * KVH_ + kv) * NSPLIT + split) * (G_ * D_);
    for (int e = tid; e < G_ * D_; e += 256) {
        float sum = 0.f;
#pragma unroll
        for (int p = 0; p < 8; p++) sum += red[p * (G_ * D_) + e];
        part_o[obase + e] = sum;
    }
    if (tid == 0) {
#pragma unroll
        for (int g = 0; g < G_; g++) {
            part_ml[mlbase + g * 2 + 0] = M[g];
            part_ml[mlbase + g * 2 + 1] = L[g];
        }
    }
}

// ---------------------------------------------------------------------------
// Kernel 2: merge NSPLIT partials per (b, kvh) via log-sum-exp combination.
// ---------------------------------------------------------------------------
__global__ __launch_bounds__(256) void attn_reduce(
    const float* __restrict__ part_o,
    const float* __restrict__ part_ml,
    float*       __restrict__ out)  // [B,H,D]
{
    const int bid = blockIdx.x;  // b*KVH + kv
    const int tid = threadIdx.x;

    __shared__ float sc[G_][NSPLIT];
    __shared__ float Ls[G_];

    if (tid < G_) {
        float m = -__builtin_inff();
        float lv[NSPLIT], mv[NSPLIT];
#pragma unroll
        for (int s = 0; s < NSPLIT; s++) {
            mv[s] = part_ml[((size_t)bid * NSPLIT + s) * G_ * 2 + tid * 2 + 0];
            lv[s] = part_ml[((size_t)bid * NSPLIT + s) * G_ * 2 + tid * 2 + 1];
            if (lv[s] > 0.f) m = fmaxf(m, mv[s]);
        }
        float L = 0.f;
#pragma unroll
        for (int s = 0; s < NSPLIT; s++) {
            float f = (lv[s] > 0.f) ? __expf(mv[s] - m) : 0.f;
            sc[tid][s] = f;
            L += f * lv[s];
        }
        Ls[tid] = L;
    }
    __syncthreads();

    for (int e = tid; e < G_ * D_; e += 256) {
        int g = e >> 7;
        float a = 0.f;
#pragma unroll
        for (int s = 0; s < NSPLIT; s++) {
            float f = sc[g][s];
            if (f != 0.f)
                a += f * part_o[((size_t)bid * NSPLIT + s) * (G_ * D_) + e];
        }
        out[(size_t)bid * (G_ * D_) + e] = a / Ls[g];
    }
}

extern "C" void kernel_launch(void* const* d_in, const int* in_sizes, int n_in,
                              void* d_out, int out_size, void* d_ws, size_t ws_size,
                              hipStream_t stream) {
    const float* q   = (const float*)d_in[0];
    const float* kc  = (const float*)d_in[1];
    const float* vc  = (const float*)d_in[2];
    const int*   bt  = (const int*)d_in[3];
    const int*   ctx = (const int*)d_in[4];
    float* out = (float*)d_out;

    float* part_o  = (float*)d_ws;  // B*KVH*NSPLIT*G*D floats = 4 MB
    float* part_ml = part_o + (size_t)B_ * KVH_ * NSPLIT * G_ * D_;  // +16 KB

    attn_partial<<<B_ * KVH_ * NSPLIT, 256, 0, stream>>>(q, kc, vc, bt, ctx,
                                                         part_o, part_ml);
    attn_reduce<<<B_ * KVH_, 256, 0, stream>>>(part_o, part_ml, out);
}